// Round 11
// baseline (271.750 us; speedup 1.0000x reference)
//
#include <hip/hip_runtime.h>
#include <hip/hip_bf16.h>
#include <math.h>

// ---------------------------------------------------------------------------
// KAN 2-layer forward, R11 = R10 INSTRUMENTATION: kgemm x16, klayer2r x32
// (idempotent reps, numerics identical).  kconv unamplified -> by subtraction.
// True per-kernel time = dispatch dur / REP; per-rep traffic = FETCH/REP.
// ---------------------------------------------------------------------------

#define B_DIM   128
#define IN1     3072
#define OUT1    256
#define NB      8
#define OUT2    10

#define KTOT    27648            // 9 * 3072
#define ROWB    55296            // KTOT * 2 bytes per row
#define SPLITK  108              // k-chunks (each 256 k = 4 stages of 64 k)
#define BN      64

#define REP_G   16
#define REP_R   32

typedef short  bf16x8 __attribute__((ext_vector_type(8)));
typedef float  f32x4  __attribute__((ext_vector_type(4)));
typedef unsigned short ushort_t;
typedef unsigned int u32;

__device__ __forceinline__ ushort_t f2bf(float f) {
    union { __hip_bfloat16 h; ushort_t u; } v;
    v.h = __float2bfloat16(f);
    return v.u;
}
__device__ __forceinline__ float bf2f(ushort_t h) {
    union { float f; u32 u; } v; v.u = ((u32)h) << 16;
    return v.f;
}

__device__ __forceinline__ void gl_lds16(const void* g, void* l) {
    __builtin_amdgcn_global_load_lds(
        (const __attribute__((address_space(1))) u32*)g,
        (__attribute__((address_space(3))) u32*)l, 16, 0, 0);
}

// cardinal cubic B-spline basis (8 funcs) + silu, closed form (== Cox-de Boor
// recursion of the reference on the uniform extended grid [-2.2,2.2], h=0.4).
__device__ __forceinline__ void basis_silu(float x, float w[8], float& sil) {
    sil = x / (1.0f + __expf(-x));
    float u  = (x + 2.2f) * 2.5f;
    float uf = floorf(u);
    int   j  = (int)uf;
    float t  = u - uf;
    float omt = 1.0f - t;
    float t2 = t * t, t3 = t2 * t;
    float w0 = omt * omt * omt * (1.0f / 6.0f);
    float w1 = (3.0f * t3 - 6.0f * t2 + 4.0f) * (1.0f / 6.0f);
    float w2 = (-3.0f * t3 + 3.0f * t2 + 3.0f * t + 1.0f) * (1.0f / 6.0f);
    float w3 = t3 * (1.0f / 6.0f);
    bool valid = (u >= 0.0f) && (u < 11.0f);
#pragma unroll
    for (int g = 0; g < 8; ++g) {
        int m = g - j + 3;
        float v = (m == 0) ? w0 : (m == 1) ? w1 : (m == 2) ? w2 : (m == 3) ? w3 : 0.0f;
        w[g] = valid ? v : 0.0f;
    }
}

__device__ __forceinline__ float selu_f(float x) {
    const float scale = 1.0507009873554805f;
    const float alpha = 1.6732632423543772f;
    return (x > 0.0f) ? scale * x : scale * alpha * (__expf(x) - 1.0f);
}

// ---------------------------------------------------------------------------
// kconv: 1152 blocks x 128 thr.  Blocks 0..383: A-conversion; 384..1151: W.
// (unamplified)
// ---------------------------------------------------------------------------
__global__ __launch_bounds__(128) void kconv(const float* __restrict__ x,
                                             const float* __restrict__ coef1,
                                             const float* __restrict__ sb1,
                                             const float* __restrict__ ssp1,
                                             char* __restrict__ Ag,
                                             char* __restrict__ Wg) {
    const int blk = blockIdx.x;
    if (blk < 384) {
        const int gid = blk * 128 + threadIdx.x;           // 0..49151
        const int b  = gid / 384;
        const int ig = gid - b * 384;
        const int i0 = ig * 8;

        float4 x0 = *reinterpret_cast<const float4*>(x + (size_t)b * IN1 + i0);
        float4 x1 = *reinterpret_cast<const float4*>(x + (size_t)b * IN1 + i0 + 4);
        float xa[8] = {x0.x, x0.y, x0.z, x0.w, x1.x, x1.y, x1.z, x1.w};

        float bs[8][8], sil[8];
#pragma unroll
        for (int p = 0; p < 8; ++p) basis_silu(xa[p], bs[p], sil[p]);

        char* rowp = Ag + (size_t)b * ROWB;
        const int qsw = ((ig & 7) ^ (b & 7)) << 4;
#pragma unroll
        for (int s = 0; s < 9; ++s) {
            ushort_t v[8];
#pragma unroll
            for (int p = 0; p < 8; ++p)
                v[p] = f2bf((s < 8) ? bs[p][s] : sil[p]);
            *reinterpret_cast<uint4*>(rowp + (s * 48 + (ig >> 3)) * 128 + qsw) =
                *reinterpret_cast<const uint4*>(v);
        }
    } else {
        const int gid = (blk - 384) * 128 + threadIdx.x;   // 0..98303
        const int o  = gid / 384;
        const int ig = gid - o * 384;
        const int i0 = ig * 8;

        float cf[8][8], sspv[8], sbv[8];
#pragma unroll
        for (int p = 0; p < 8; ++p) {
            const float* cp = coef1 + ((size_t)o * IN1 + i0 + p) * NB;
            float4 c0 = *reinterpret_cast<const float4*>(cp);
            float4 c1 = *reinterpret_cast<const float4*>(cp + 4);
            cf[p][0] = c0.x; cf[p][1] = c0.y; cf[p][2] = c0.z; cf[p][3] = c0.w;
            cf[p][4] = c1.x; cf[p][5] = c1.y; cf[p][6] = c1.z; cf[p][7] = c1.w;
        }
        {
            float4 s0 = *reinterpret_cast<const float4*>(ssp1 + (size_t)o * IN1 + i0);
            float4 s1 = *reinterpret_cast<const float4*>(ssp1 + (size_t)o * IN1 + i0 + 4);
            sspv[0]=s0.x; sspv[1]=s0.y; sspv[2]=s0.z; sspv[3]=s0.w;
            sspv[4]=s1.x; sspv[5]=s1.y; sspv[6]=s1.z; sspv[7]=s1.w;
            float4 b0 = *reinterpret_cast<const float4*>(sb1 + (size_t)o * IN1 + i0);
            float4 b1 = *reinterpret_cast<const float4*>(sb1 + (size_t)o * IN1 + i0 + 4);
            sbv[0]=b0.x; sbv[1]=b0.y; sbv[2]=b0.z; sbv[3]=b0.w;
            sbv[4]=b1.x; sbv[5]=b1.y; sbv[6]=b1.z; sbv[7]=b1.w;
        }

        char* rowp = Wg + (size_t)o * ROWB;
        const int qsw = ((ig & 7) ^ (o & 7)) << 4;
#pragma unroll
        for (int s = 0; s < 9; ++s) {
            ushort_t v[8];
#pragma unroll
            for (int p = 0; p < 8; ++p)
                v[p] = f2bf((s < 8) ? cf[p][s] * sspv[p] : sbv[p]);
            *reinterpret_cast<uint4*>(rowp + (s * 48 + (ig >> 3)) * 128 + qsw) =
                *reinterpret_cast<const uint4*>(v);
        }
    }
}

// ---------------------------------------------------------------------------
// kgemm (REP_G amplified): C(128x64) += A(128,256k)*W(256k,64).  grid (4,108).
// ---------------------------------------------------------------------------
__global__ __launch_bounds__(512) void kgemm(const char* __restrict__ Ag,
                                             const char* __restrict__ Wg,
                                             ushort_t* __restrict__ partial) {
    __shared__ __align__(16) char lds[2][24576];   // per buf: A 16K | W 8K

    const int tid = threadIdx.x;
    const int w   = tid >> 6, l = tid & 63;
    const int nt  = blockIdx.x, kc = blockIdx.y;
    const int o0  = nt * BN;

    const int ar0 = tid >> 3;                 // A round 0: rows 0..63
    const int ar1 = 64 + (tid >> 3);          // A round 1: rows 64..127
    const int aq  = tid & 7;
    const char* Asrc0 = Ag + (size_t)ar0 * ROWB + ((aq ^ (ar0 & 7)) << 4);
    const char* Asrc1 = Ag + (size_t)ar1 * ROWB + ((aq ^ (ar1 & 7)) << 4);
    const int wr = tid >> 3;                  // W rows 0..63
    const char* Wsrc = Wg + (size_t)(o0 + wr) * ROWB + ((aq ^ (wr & 7)) << 4);

    const int mq = w >> 1, nq = w & 1;
    const int r16 = l & 15, k16 = l >> 4;

#define ISSUE(ss, buf)                                                        \
    {                                                                         \
        const int cb = (kc * 4 + (ss)) * 128;                                 \
        char* base = &lds[buf][0];                                            \
        gl_lds16(Asrc0 + cb, base + w * 1024);                                \
        gl_lds16(Asrc1 + cb, base + 8192 + w * 1024);                         \
        gl_lds16(Wsrc  + cb, base + 16384 + w * 1024);                        \
    }

#pragma unroll 1
    for (int rep = 0; rep < REP_G; ++rep) {
        asm volatile("" ::: "memory");
        f32x4 acc[2][2];
#pragma unroll
        for (int a = 0; a < 2; ++a)
#pragma unroll
            for (int bq = 0; bq < 2; ++bq) acc[a][bq] = (f32x4){0.f, 0.f, 0.f, 0.f};

        ISSUE(0, 0)
        ISSUE(1, 1)

#pragma unroll
        for (int s = 0; s < 4; ++s) {
            if (s < 3) { asm volatile("s_waitcnt vmcnt(3)" ::: "memory"); }
            else       { asm volatile("s_waitcnt vmcnt(0)" ::: "memory"); }
            __builtin_amdgcn_s_barrier();
            asm volatile("" ::: "memory");

            const char* Ab = &lds[s & 1][0];
            const char* Wb = &lds[s & 1][16384];
#pragma unroll
            for (int ks = 0; ks < 2; ++ks) {
                const int qf = ks * 4 + k16;
                bf16x8 bf[2], af[2];
#pragma unroll
                for (int bq = 0; bq < 2; ++bq) {
                    const int rn = nq * 32 + bq * 16 + r16;
                    bf[bq] = *reinterpret_cast<const bf16x8*>(Wb + rn * 128 + ((qf ^ (rn & 7)) << 4));
                }
#pragma unroll
                for (int a = 0; a < 2; ++a) {
                    const int rm = mq * 32 + a * 16 + r16;
                    af[a] = *reinterpret_cast<const bf16x8*>(Ab + rm * 128 + ((qf ^ (rm & 7)) << 4));
                }
#pragma unroll
                for (int a = 0; a < 2; ++a)
#pragma unroll
                    for (int bq = 0; bq < 2; ++bq)
                        acc[a][bq] = __builtin_amdgcn_mfma_f32_16x16x32_bf16(af[a], bf[bq], acc[a][bq], 0, 0, 0);
            }

            __builtin_amdgcn_s_barrier();
            asm volatile("" ::: "memory");
            if (s == 0) ISSUE(2, 0)
            if (s == 1) ISSUE(3, 1)
        }

        // epilogue: bf16 partial [kc][b][o]
        ushort_t* pp = partial + (size_t)kc * (B_DIM * OUT1);
#pragma unroll
        for (int a = 0; a < 2; ++a) {
#pragma unroll
            for (int bq = 0; bq < 2; ++bq) {
                const int col = o0 + nq * 32 + bq * 16 + r16;
#pragma unroll
                for (int r = 0; r < 4; ++r) {
                    const int row = mq * 32 + a * 16 + k16 * 4 + r;
                    pp[(size_t)row * OUT1 + col] = f2bf(acc[a][bq][r]);
                }
            }
        }
        __syncthreads();
    }
#undef ISSUE
}

// ---------------------------------------------------------------------------
// klayer2r (REP_R amplified): per-b block; 4 waves x 27 contiguous 512B loads.
// ---------------------------------------------------------------------------
__global__ __launch_bounds__(256) void klayer2r(const ushort_t* __restrict__ partial,
                                                const float* __restrict__ coef2,
                                                const float* __restrict__ sb2,
                                                const float* __restrict__ ssp2,
                                                float* __restrict__ out) {
    const int b = blockIdx.x;
    const int t = threadIdx.x;
    const int w = t >> 6, l = t & 63;
    __shared__ float sums[4][OUT1];
    __shared__ float red[4][OUT2];

#pragma unroll 1
    for (int rep = 0; rep < REP_R; ++rep) {
        asm volatile("" ::: "memory");
        f32x4 s = {0.f, 0.f, 0.f, 0.f};
        const ushort_t* pb = partial + (size_t)b * OUT1 + l * 4;
#pragma unroll
        for (int c = 0; c < 27; ++c) {
            ushort4 v = *reinterpret_cast<const ushort4*>(
                pb + (size_t)(w + 4 * c) * (B_DIM * OUT1));
            s[0] += bf2f(v.x); s[1] += bf2f(v.y); s[2] += bf2f(v.z); s[3] += bf2f(v.w);
        }

        *reinterpret_cast<float4*>(&sums[w][l * 4]) = (float4){s[0], s[1], s[2], s[3]};
        __syncthreads();

        const float hv = sums[0][t] + sums[1][t] + sums[2][t] + sums[3][t];
        const float sh = selu_f(hv);
        float w8[8], sil;
        basis_silu(sh, w8, sil);

        float accs[OUT2];
#pragma unroll
        for (int oo = 0; oo < OUT2; ++oo) {
            const float* cp = coef2 + ((size_t)oo * OUT1 + t) * NB;
            float4 c0 = *reinterpret_cast<const float4*>(cp);
            float4 c1 = *reinterpret_cast<const float4*>(cp + 4);
            float dot = w8[0] * c0.x + w8[1] * c0.y + w8[2] * c0.z + w8[3] * c0.w +
                        w8[4] * c1.x + w8[5] * c1.y + w8[6] * c1.z + w8[7] * c1.w;
            accs[oo] = sb2[oo * OUT1 + t] * sil + ssp2[oo * OUT1 + t] * dot;
        }

#pragma unroll
        for (int oo = 0; oo < OUT2; ++oo) {
            float v = accs[oo];
#pragma unroll
            for (int off = 32; off >= 1; off >>= 1) v += __shfl_xor(v, off, 64);
            if (l == 0) red[w][oo] = v;
        }
        __syncthreads();
        if (t < OUT2)
            out[b * OUT2 + t] = red[0][t] + red[1][t] + red[2][t] + red[3][t];
        __syncthreads();
    }
}

// ---------------------------------------------------------------------------
extern "C" void kernel_launch(void* const* d_in, const int* in_sizes, int n_in,
                              void* d_out, int out_size, void* d_ws, size_t ws_size,
                              hipStream_t stream) {
    const float* x     = (const float*)d_in[0];
    const float* coef1 = (const float*)d_in[1];
    const float* sb1   = (const float*)d_in[2];
    const float* ssp1  = (const float*)d_in[3];
    const float* coef2 = (const float*)d_in[4];
    const float* sb2   = (const float*)d_in[5];
    const float* ssp2  = (const float*)d_in[6];
    float* out = (float*)d_out;

    char*     Ag      = (char*)d_ws;                             // 7,077,888 B
    char*     Wg      = Ag + (size_t)B_DIM * ROWB;               // 14,155,776 B
    ushort_t* partial = (ushort_t*)(Wg + (size_t)OUT1 * ROWB);   // 7,077,888 B

    kconv<<<1152, 128, 0, stream>>>(x, coef1, sb1, ssp1, Ag, Wg);
    kgemm<<<dim3(OUT1 / BN, SPLITK), 512, 0, stream>>>(Ag, Wg, partial);
    klayer2r<<<B_DIM, 256, 0, stream>>>(partial, coef2, sb2, ssp2, out);
}

// Round 12
// 38.106 us; speedup vs baseline: 7.1315x; 7.1315x over previous
//
#include <hip/hip_runtime.h>
#include <hip/hip_bf16.h>
#include <math.h>

// ---------------------------------------------------------------------------
// KAN 2-layer forward, R12: R10 with conversion geometry fixed (R11 verdict:
// kconv was 25.4us of the 36.3 -- register-bloated band-transpose at 9
// waves/CU).  Conversion now does the band-transpose through LDS with ~25
// VGPRs/thread and 256-thread blocks; layouts and kgemm are bit-identical.
//   kconv_a : x -> Ag bf16 (basis|silu bands, swizzled quads)      ~8.6 MB
//   kconv_w : coef1*ssp1|sb1 -> Wg bf16 (same band layout)         ~45.7 MB
//   kgemm   : MFMA split-K=108, global_load_lds pipeline (unchanged)
//   klayer2r: 8-wave partial reduce + selu + layer2 (2x occupancy)
// ---------------------------------------------------------------------------

#define B_DIM   128
#define IN1     3072
#define OUT1    256
#define NB      8
#define OUT2    10

#define KTOT    27648            // 9 * 3072
#define ROWB    55296            // KTOT * 2 bytes per row
#define SPLITK  108              // k-chunks (each 256 k = 4 stages of 64 k)
#define BN      64

typedef short  bf16x8 __attribute__((ext_vector_type(8)));
typedef float  f32x4  __attribute__((ext_vector_type(4)));
typedef unsigned short ushort_t;
typedef unsigned int u32;

__device__ __forceinline__ ushort_t f2bf(float f) {
    union { __hip_bfloat16 h; ushort_t u; } v;
    v.h = __float2bfloat16(f);
    return v.u;
}
__device__ __forceinline__ float bf2f(ushort_t h) {
    union { float f; u32 u; } v; v.u = ((u32)h) << 16;
    return v.f;
}

__device__ __forceinline__ void gl_lds16(const void* g, void* l) {
    __builtin_amdgcn_global_load_lds(
        (const __attribute__((address_space(1))) u32*)g,
        (__attribute__((address_space(3))) u32*)l, 16, 0, 0);
}

// cardinal cubic B-spline basis (8 funcs) + silu, closed form (== Cox-de Boor
// recursion of the reference on the uniform extended grid [-2.2,2.2], h=0.4).
__device__ __forceinline__ void basis_silu(float x, float w[8], float& sil) {
    sil = x / (1.0f + __expf(-x));
    float u  = (x + 2.2f) * 2.5f;
    float uf = floorf(u);
    int   j  = (int)uf;
    float t  = u - uf;
    float omt = 1.0f - t;
    float t2 = t * t, t3 = t2 * t;
    float w0 = omt * omt * omt * (1.0f / 6.0f);
    float w1 = (3.0f * t3 - 6.0f * t2 + 4.0f) * (1.0f / 6.0f);
    float w2 = (-3.0f * t3 + 3.0f * t2 + 3.0f * t + 1.0f) * (1.0f / 6.0f);
    float w3 = t3 * (1.0f / 6.0f);
    bool valid = (u >= 0.0f) && (u < 11.0f);
#pragma unroll
    for (int g = 0; g < 8; ++g) {
        int m = g - j + 3;
        float v = (m == 0) ? w0 : (m == 1) ? w1 : (m == 2) ? w2 : (m == 3) ? w3 : 0.0f;
        w[g] = valid ? v : 0.0f;
    }
}

__device__ __forceinline__ float selu_f(float x) {
    const float scale = 1.0507009873554805f;
    const float alpha = 1.6732632423543772f;
    return (x > 0.0f) ? scale * x : scale * alpha * (__expf(x) - 1.0f);
}

// ---------------------------------------------------------------------------
// kconv_a: 384 blocks x 256 thr.  Block: (b = blk/3, i0 = (blk%3)*1024).
//   Load: thread -> 4 inputs (float4), basis+silu, 9 bf16 each -> LDS.
//   Store: 1152 16B units band-major, swizzled quads (layout == old kconv).
// ---------------------------------------------------------------------------
#define APAD 8
__global__ __launch_bounds__(256) void kconv_a(const float* __restrict__ x,
                                               char* __restrict__ Ag) {
    __shared__ ushort_t lds[9][1024 + APAD];
    const int tid = threadIdx.x;
    const int b  = blockIdx.x / 3;
    const int i0 = (blockIdx.x % 3) * 1024;

    {
        const int li = tid * 4;
        float4 xv = *reinterpret_cast<const float4*>(x + (size_t)b * IN1 + i0 + li);
        float xa[4] = {xv.x, xv.y, xv.z, xv.w};
#pragma unroll
        for (int p = 0; p < 4; ++p) {
            float bs[8], sil;
            basis_silu(xa[p], bs, sil);
#pragma unroll
            for (int s = 0; s < 8; ++s) lds[s][li + p] = f2bf(bs[s]);
            lds[8][li + p] = f2bf(sil);
        }
    }
    __syncthreads();

    char* rowp = Ag + (size_t)b * ROWB;
    const int bsw = b & 7;
#pragma unroll
    for (int r = 0; r < 5; ++r) {
        const int u = tid + r * 256;
        if (u < 1152) {
            const int s = u >> 7, q = u & 127;
            const int ig = (i0 >> 3) + q;
            uint4 v = *reinterpret_cast<const uint4*>(&lds[s][q * 8]);
            *reinterpret_cast<uint4*>(rowp + (s * 48 + (ig >> 3)) * 128 +
                                      (((ig & 7) ^ bsw) << 4)) = v;
        }
    }
}

// ---------------------------------------------------------------------------
// kconv_w: 1536 blocks x 256 thr.  Block: (o = blk/6, i0 = (blk%6)*512).
//   Load: thread -> 2 inputs (64B coef contiguous + float2 ssp + float2 sb).
//   Store: 576 16B units band-major, swizzled quads (layout == old kconv).
// ---------------------------------------------------------------------------
#define WPAD 16
__global__ __launch_bounds__(256) void kconv_w(const float* __restrict__ coef1,
                                               const float* __restrict__ sb1,
                                               const float* __restrict__ ssp1,
                                               char* __restrict__ Wg) {
    __shared__ ushort_t lds[9][512 + WPAD];
    const int tid = threadIdx.x;
    const int o  = blockIdx.x / 6;
    const int i0 = (blockIdx.x % 6) * 512;

    {
        const int li = tid * 2;
        const size_t e = (size_t)o * IN1 + i0 + li;
        const float* cp = coef1 + e * NB;
        float4 c0 = *reinterpret_cast<const float4*>(cp);
        float4 c1 = *reinterpret_cast<const float4*>(cp + 4);
        float4 c2 = *reinterpret_cast<const float4*>(cp + 8);
        float4 c3 = *reinterpret_cast<const float4*>(cp + 12);
        float2 sspv = *reinterpret_cast<const float2*>(ssp1 + e);
        float2 sbv  = *reinterpret_cast<const float2*>(sb1 + e);

        lds[0][li] = f2bf(c0.x * sspv.x); lds[1][li] = f2bf(c0.y * sspv.x);
        lds[2][li] = f2bf(c0.z * sspv.x); lds[3][li] = f2bf(c0.w * sspv.x);
        lds[4][li] = f2bf(c1.x * sspv.x); lds[5][li] = f2bf(c1.y * sspv.x);
        lds[6][li] = f2bf(c1.z * sspv.x); lds[7][li] = f2bf(c1.w * sspv.x);
        lds[8][li] = f2bf(sbv.x);
        lds[0][li+1] = f2bf(c2.x * sspv.y); lds[1][li+1] = f2bf(c2.y * sspv.y);
        lds[2][li+1] = f2bf(c2.z * sspv.y); lds[3][li+1] = f2bf(c2.w * sspv.y);
        lds[4][li+1] = f2bf(c3.x * sspv.y); lds[5][li+1] = f2bf(c3.y * sspv.y);
        lds[6][li+1] = f2bf(c3.z * sspv.y); lds[7][li+1] = f2bf(c3.w * sspv.y);
        lds[8][li+1] = f2bf(sbv.y);
    }
    __syncthreads();

    char* rowp = Wg + (size_t)o * ROWB;
    const int osw = o & 7;
#pragma unroll
    for (int r = 0; r < 3; ++r) {
        const int u = tid + r * 256;
        if (u < 576) {
            const int s = u >> 6, q = u & 63;
            const int ig = (i0 >> 3) + q;
            uint4 v = *reinterpret_cast<const uint4*>(&lds[s][q * 8]);
            *reinterpret_cast<uint4*>(rowp + (s * 48 + (ig >> 3)) * 128 +
                                      (((ig & 7) ^ osw) << 4)) = v;
        }
    }
}

// ---------------------------------------------------------------------------
// kgemm: unchanged from R10.  512 thr, grid (4,108), global_load_lds pipeline.
// ---------------------------------------------------------------------------
__global__ __launch_bounds__(512) void kgemm(const char* __restrict__ Ag,
                                             const char* __restrict__ Wg,
                                             ushort_t* __restrict__ partial) {
    __shared__ __align__(16) char lds[2][24576];   // per buf: A 16K | W 8K

    const int tid = threadIdx.x;
    const int w   = tid >> 6, l = tid & 63;
    const int nt  = blockIdx.x, kc = blockIdx.y;
    const int o0  = nt * BN;

    const int ar0 = tid >> 3;                 // A round 0: rows 0..63
    const int ar1 = 64 + (tid >> 3);          // A round 1: rows 64..127
    const int aq  = tid & 7;
    const char* Asrc0 = Ag + (size_t)ar0 * ROWB + ((aq ^ (ar0 & 7)) << 4);
    const char* Asrc1 = Ag + (size_t)ar1 * ROWB + ((aq ^ (ar1 & 7)) << 4);
    const int wr = tid >> 3;                  // W rows 0..63
    const char* Wsrc = Wg + (size_t)(o0 + wr) * ROWB + ((aq ^ (wr & 7)) << 4);

#define ISSUE(ss, buf)                                                        \
    {                                                                         \
        const int cb = (kc * 4 + (ss)) * 128;                                 \
        char* base = &lds[buf][0];                                            \
        gl_lds16(Asrc0 + cb, base + w * 1024);                                \
        gl_lds16(Asrc1 + cb, base + 8192 + w * 1024);                         \
        gl_lds16(Wsrc  + cb, base + 16384 + w * 1024);                        \
    }

    f32x4 acc[2][2];
#pragma unroll
    for (int a = 0; a < 2; ++a)
#pragma unroll
        for (int bq = 0; bq < 2; ++bq) acc[a][bq] = (f32x4){0.f, 0.f, 0.f, 0.f};

    const int mq = w >> 1, nq = w & 1;
    const int r16 = l & 15, k16 = l >> 4;

    ISSUE(0, 0)
    ISSUE(1, 1)

#pragma unroll
    for (int s = 0; s < 4; ++s) {
        if (s < 3) { asm volatile("s_waitcnt vmcnt(3)" ::: "memory"); }
        else       { asm volatile("s_waitcnt vmcnt(0)" ::: "memory"); }
        __builtin_amdgcn_s_barrier();
        asm volatile("" ::: "memory");

        const char* Ab = &lds[s & 1][0];
        const char* Wb = &lds[s & 1][16384];
#pragma unroll
        for (int ks = 0; ks < 2; ++ks) {
            const int qf = ks * 4 + k16;
            bf16x8 bf[2], af[2];
#pragma unroll
            for (int bq = 0; bq < 2; ++bq) {
                const int rn = nq * 32 + bq * 16 + r16;
                bf[bq] = *reinterpret_cast<const bf16x8*>(Wb + rn * 128 + ((qf ^ (rn & 7)) << 4));
            }
#pragma unroll
            for (int a = 0; a < 2; ++a) {
                const int rm = mq * 32 + a * 16 + r16;
                af[a] = *reinterpret_cast<const bf16x8*>(Ab + rm * 128 + ((qf ^ (rm & 7)) << 4));
            }
#pragma unroll
            for (int a = 0; a < 2; ++a)
#pragma unroll
                for (int bq = 0; bq < 2; ++bq)
                    acc[a][bq] = __builtin_amdgcn_mfma_f32_16x16x32_bf16(af[a], bf[bq], acc[a][bq], 0, 0, 0);
        }

        __builtin_amdgcn_s_barrier();
        asm volatile("" ::: "memory");
        if (s == 0) ISSUE(2, 0)
        if (s == 1) ISSUE(3, 1)
    }
#undef ISSUE

    // epilogue: bf16 partial [kc][b][o]
    ushort_t* pp = partial + (size_t)kc * (B_DIM * OUT1);
#pragma unroll
    for (int a = 0; a < 2; ++a) {
#pragma unroll
        for (int bq = 0; bq < 2; ++bq) {
            const int col = o0 + nq * 32 + bq * 16 + r16;
#pragma unroll
            for (int r = 0; r < 4; ++r) {
                const int row = mq * 32 + a * 16 + k16 * 4 + r;
                pp[(size_t)row * OUT1 + col] = f2bf(acc[a][bq][r]);
            }
        }
    }
}

// ---------------------------------------------------------------------------
// klayer2r: one block per b, 512 thr (8 waves).  Wave w sums kc = w+8c
// (13 or 14 chunks) with 512B-contiguous wave-loads; LDS combine -> h ->
// selu -> basis -> layer2 -> out.
// ---------------------------------------------------------------------------
__global__ __launch_bounds__(512) void klayer2r(const ushort_t* __restrict__ partial,
                                                const float* __restrict__ coef2,
                                                const float* __restrict__ sb2,
                                                const float* __restrict__ ssp2,
                                                float* __restrict__ out) {
    const int b = blockIdx.x;
    const int t = threadIdx.x;
    const int w = t >> 6, l = t & 63;
    __shared__ float sums[8][OUT1];
    __shared__ float red[4][OUT2];

    f32x4 s = {0.f, 0.f, 0.f, 0.f};
    const ushort_t* pb = partial + (size_t)b * OUT1 + l * 4;
#pragma unroll
    for (int c = 0; c < 13; ++c) {
        ushort4 v = *reinterpret_cast<const ushort4*>(
            pb + (size_t)(w + 8 * c) * (B_DIM * OUT1));
        s[0] += bf2f(v.x); s[1] += bf2f(v.y); s[2] += bf2f(v.z); s[3] += bf2f(v.w);
    }
    if (w < 4) {
        ushort4 v = *reinterpret_cast<const ushort4*>(
            pb + (size_t)(w + 104) * (B_DIM * OUT1));
        s[0] += bf2f(v.x); s[1] += bf2f(v.y); s[2] += bf2f(v.z); s[3] += bf2f(v.w);
    }
    *reinterpret_cast<float4*>(&sums[w][l * 4]) = (float4){s[0], s[1], s[2], s[3]};
    __syncthreads();

    if (t < OUT1) {
        const float hv = sums[0][t] + sums[1][t] + sums[2][t] + sums[3][t] +
                         sums[4][t] + sums[5][t] + sums[6][t] + sums[7][t];
        const float sh = selu_f(hv);
        float w8[8], sil;
        basis_silu(sh, w8, sil);

        float accs[OUT2];
#pragma unroll
        for (int oo = 0; oo < OUT2; ++oo) {
            const float* cp = coef2 + ((size_t)oo * OUT1 + t) * NB;
            float4 c0 = *reinterpret_cast<const float4*>(cp);
            float4 c1 = *reinterpret_cast<const float4*>(cp + 4);
            float dot = w8[0] * c0.x + w8[1] * c0.y + w8[2] * c0.z + w8[3] * c0.w +
                        w8[4] * c1.x + w8[5] * c1.y + w8[6] * c1.z + w8[7] * c1.w;
            accs[oo] = sb2[oo * OUT1 + t] * sil + ssp2[oo * OUT1 + t] * dot;
        }

#pragma unroll
        for (int oo = 0; oo < OUT2; ++oo) {
            float v = accs[oo];
#pragma unroll
            for (int off = 32; off >= 1; off >>= 1) v += __shfl_xor(v, off, 64);
            if (l == 0) red[w][oo] = v;
        }
    }
    __syncthreads();
    if (t < OUT2)
        out[b * OUT2 + t] = red[0][t] + red[1][t] + red[2][t] + red[3][t];
}

// ---------------------------------------------------------------------------
extern "C" void kernel_launch(void* const* d_in, const int* in_sizes, int n_in,
                              void* d_out, int out_size, void* d_ws, size_t ws_size,
                              hipStream_t stream) {
    const float* x     = (const float*)d_in[0];
    const float* coef1 = (const float*)d_in[1];
    const float* sb1   = (const float*)d_in[2];
    const float* ssp1  = (const float*)d_in[3];
    const float* coef2 = (const float*)d_in[4];
    const float* sb2   = (const float*)d_in[5];
    const float* ssp2  = (const float*)d_in[6];
    float* out = (float*)d_out;

    char*     Ag      = (char*)d_ws;                             // 7,077,888 B
    char*     Wg      = Ag + (size_t)B_DIM * ROWB;               // 14,155,776 B
    ushort_t* partial = (ushort_t*)(Wg + (size_t)OUT1 * ROWB);   // 7,077,888 B

    kconv_a<<<384, 256, 0, stream>>>(x, Ag);
    kconv_w<<<1536, 256, 0, stream>>>(coef1, sb1, ssp1, Wg);
    kgemm<<<dim3(OUT1 / BN, SPLITK), 512, 0, stream>>>(Ag, Wg, partial);
    klayer2r<<<B_DIM, 512, 0, stream>>>(partial, coef2, sb2, ssp2, out);
}

// Round 13
// 38.083 us; speedup vs baseline: 7.1357x; 1.0006x over previous
//
#include <hip/hip_runtime.h>
#include <hip/hip_bf16.h>
#include <math.h>

// ---------------------------------------------------------------------------
// KAN 2-layer forward, R13: R12 with conv_w's global reads made lane-
// contiguous (R12 null-result autopsy: both conv variants read coef1 with
// 64-256B lane stride -> 64 cache lines per wave-load -> ~1.8 TB/s; probes
// reading the same buffer lane-contiguous hit ~5 TB/s).
//   kconv_a : unchanged from R12 (x reads already coalesced)
//   kconv_w : phase1 coalesced raw load -> band-major f32 LDS;
//             phase2 contiguous LDS b128 -> convert -> swizzled 16B stores
//   kgemm   : unchanged (MFMA split-K=108, global_load_lds pipeline)
//   klayer2r: unchanged (8-wave reduce + selu + layer2)
// ---------------------------------------------------------------------------

#define B_DIM   128
#define IN1     3072
#define OUT1    256
#define NB      8
#define OUT2    10

#define KTOT    27648            // 9 * 3072
#define ROWB    55296            // KTOT * 2 bytes per row
#define SPLITK  108              // k-chunks (each 256 k = 4 stages of 64 k)
#define BN      64

typedef short  bf16x8 __attribute__((ext_vector_type(8)));
typedef float  f32x4  __attribute__((ext_vector_type(4)));
typedef unsigned short ushort_t;
typedef unsigned int u32;

__device__ __forceinline__ ushort_t f2bf(float f) {
    union { __hip_bfloat16 h; ushort_t u; } v;
    v.h = __float2bfloat16(f);
    return v.u;
}
__device__ __forceinline__ float bf2f(ushort_t h) {
    union { float f; u32 u; } v; v.u = ((u32)h) << 16;
    return v.f;
}

__device__ __forceinline__ void gl_lds16(const void* g, void* l) {
    __builtin_amdgcn_global_load_lds(
        (const __attribute__((address_space(1))) u32*)g,
        (__attribute__((address_space(3))) u32*)l, 16, 0, 0);
}

// cardinal cubic B-spline basis (8 funcs) + silu, closed form (== Cox-de Boor
// recursion of the reference on the uniform extended grid [-2.2,2.2], h=0.4).
__device__ __forceinline__ void basis_silu(float x, float w[8], float& sil) {
    sil = x / (1.0f + __expf(-x));
    float u  = (x + 2.2f) * 2.5f;
    float uf = floorf(u);
    int   j  = (int)uf;
    float t  = u - uf;
    float omt = 1.0f - t;
    float t2 = t * t, t3 = t2 * t;
    float w0 = omt * omt * omt * (1.0f / 6.0f);
    float w1 = (3.0f * t3 - 6.0f * t2 + 4.0f) * (1.0f / 6.0f);
    float w2 = (-3.0f * t3 + 3.0f * t2 + 3.0f * t + 1.0f) * (1.0f / 6.0f);
    float w3 = t3 * (1.0f / 6.0f);
    bool valid = (u >= 0.0f) && (u < 11.0f);
#pragma unroll
    for (int g = 0; g < 8; ++g) {
        int m = g - j + 3;
        float v = (m == 0) ? w0 : (m == 1) ? w1 : (m == 2) ? w2 : (m == 3) ? w3 : 0.0f;
        w[g] = valid ? v : 0.0f;
    }
}

__device__ __forceinline__ float selu_f(float x) {
    const float scale = 1.0507009873554805f;
    const float alpha = 1.6732632423543772f;
    return (x > 0.0f) ? scale * x : scale * alpha * (__expf(x) - 1.0f);
}

// ---------------------------------------------------------------------------
// kconv_a: 384 blocks x 256 thr (unchanged from R12).
// ---------------------------------------------------------------------------
#define APAD 8
__global__ __launch_bounds__(256) void kconv_a(const float* __restrict__ x,
                                               char* __restrict__ Ag) {
    __shared__ ushort_t lds[9][1024 + APAD];
    const int tid = threadIdx.x;
    const int b  = blockIdx.x / 3;
    const int i0 = (blockIdx.x % 3) * 1024;

    {
        const int li = tid * 4;
        float4 xv = *reinterpret_cast<const float4*>(x + (size_t)b * IN1 + i0 + li);
        float xa[4] = {xv.x, xv.y, xv.z, xv.w};
#pragma unroll
        for (int p = 0; p < 4; ++p) {
            float bs[8], sil;
            basis_silu(xa[p], bs, sil);
#pragma unroll
            for (int s = 0; s < 8; ++s) lds[s][li + p] = f2bf(bs[s]);
            lds[8][li + p] = f2bf(sil);
        }
    }
    __syncthreads();

    char* rowp = Ag + (size_t)b * ROWB;
    const int bsw = b & 7;
#pragma unroll
    for (int r = 0; r < 5; ++r) {
        const int u = tid + r * 256;
        if (u < 1152) {
            const int s = u >> 7, q = u & 127;
            const int ig = (i0 >> 3) + q;
            uint4 v = *reinterpret_cast<const uint4*>(&lds[s][q * 8]);
            *reinterpret_cast<uint4*>(rowp + (s * 48 + (ig >> 3)) * 128 +
                                      (((ig & 7) ^ bsw) << 4)) = v;
        }
    }
}

// ---------------------------------------------------------------------------
// kconv_w: 768 blocks x 256 thr.  Block: (o = blk/3, i0 = (blk%3)*1024).
//   Phase 1: lane-contiguous raw loads (coef 32KB as 8 wave-contiguous
//            float4 rounds; ssp/sb 4KB each) -> band-major f32 LDS.
//   Phase 2: per-unit contiguous LDS b128 -> *ssp -> bf16 -> swizzled store.
// ---------------------------------------------------------------------------
#define WROWD 1032
__global__ __launch_bounds__(256) void kconv_w(const float* __restrict__ coef1,
                                               const float* __restrict__ sb1,
                                               const float* __restrict__ ssp1,
                                               char* __restrict__ Wg) {
    __shared__ float cb[8][WROWD];     // band-major coef f32  (33 KB)
    __shared__ float sspl[1024];       // 4 KB
    __shared__ float sbl[1024];        // 4 KB
    const int tid = threadIdx.x;
    const int o  = blockIdx.x / 3;
    const int i0 = (blockIdx.x % 3) * 1024;

    // ---- phase 1: coalesced raw load + band de-interleave ----
    {
        const float* cbase = coef1 + ((size_t)o * IN1 + i0) * NB;
        const int s0 = (tid & 1) * 4;
        const int ih = tid >> 1;
#pragma unroll
        for (int j = 0; j < 8; ++j) {
            float4 c = *reinterpret_cast<const float4*>(cbase + j * 1024 + tid * 4);
            const int iloc = j * 128 + ih;
            cb[s0 + 0][iloc] = c.x;
            cb[s0 + 1][iloc] = c.y;
            cb[s0 + 2][iloc] = c.z;
            cb[s0 + 3][iloc] = c.w;
        }
        float4 sv = *reinterpret_cast<const float4*>(ssp1 + (size_t)o * IN1 + i0 + tid * 4);
        *reinterpret_cast<float4*>(&sspl[tid * 4]) = sv;
        float4 bv = *reinterpret_cast<const float4*>(sb1 + (size_t)o * IN1 + i0 + tid * 4);
        *reinterpret_cast<float4*>(&sbl[tid * 4]) = bv;
    }
    __syncthreads();

    // ---- phase 2: contiguous LDS reads -> convert -> swizzled 16B stores ----
    char* rowp = Wg + (size_t)o * ROWB;
    const int osw = o & 7;
#pragma unroll
    for (int r = 0; r < 5; ++r) {
        const int u = tid + r * 256;
        if (u < 1152) {
            const int s = u >> 7, q = u & 127;
            const int ig = (i0 >> 3) + q;
            ushort_t v[8];
            if (s < 8) {
                float4 ca = *reinterpret_cast<const float4*>(&cb[s][q * 8]);
                float4 cc = *reinterpret_cast<const float4*>(&cb[s][q * 8 + 4]);
                float4 sa = *reinterpret_cast<const float4*>(&sspl[q * 8]);
                float4 sc = *reinterpret_cast<const float4*>(&sspl[q * 8 + 4]);
                v[0] = f2bf(ca.x * sa.x); v[1] = f2bf(ca.y * sa.y);
                v[2] = f2bf(ca.z * sa.z); v[3] = f2bf(ca.w * sa.w);
                v[4] = f2bf(cc.x * sc.x); v[5] = f2bf(cc.y * sc.y);
                v[6] = f2bf(cc.z * sc.z); v[7] = f2bf(cc.w * sc.w);
            } else {
                float4 ba = *reinterpret_cast<const float4*>(&sbl[q * 8]);
                float4 bc = *reinterpret_cast<const float4*>(&sbl[q * 8 + 4]);
                v[0] = f2bf(ba.x); v[1] = f2bf(ba.y); v[2] = f2bf(ba.z); v[3] = f2bf(ba.w);
                v[4] = f2bf(bc.x); v[5] = f2bf(bc.y); v[6] = f2bf(bc.z); v[7] = f2bf(bc.w);
            }
            *reinterpret_cast<uint4*>(rowp + (s * 48 + (ig >> 3)) * 128 +
                                      (((ig & 7) ^ osw) << 4)) =
                *reinterpret_cast<const uint4*>(v);
        }
    }
}

// ---------------------------------------------------------------------------
// kgemm: unchanged.  512 thr, grid (4,108), global_load_lds pipeline.
// ---------------------------------------------------------------------------
__global__ __launch_bounds__(512) void kgemm(const char* __restrict__ Ag,
                                             const char* __restrict__ Wg,
                                             ushort_t* __restrict__ partial) {
    __shared__ __align__(16) char lds[2][24576];   // per buf: A 16K | W 8K

    const int tid = threadIdx.x;
    const int w   = tid >> 6, l = tid & 63;
    const int nt  = blockIdx.x, kc = blockIdx.y;
    const int o0  = nt * BN;

    const int ar0 = tid >> 3;                 // A round 0: rows 0..63
    const int ar1 = 64 + (tid >> 3);          // A round 1: rows 64..127
    const int aq  = tid & 7;
    const char* Asrc0 = Ag + (size_t)ar0 * ROWB + ((aq ^ (ar0 & 7)) << 4);
    const char* Asrc1 = Ag + (size_t)ar1 * ROWB + ((aq ^ (ar1 & 7)) << 4);
    const int wr = tid >> 3;                  // W rows 0..63
    const char* Wsrc = Wg + (size_t)(o0 + wr) * ROWB + ((aq ^ (wr & 7)) << 4);

#define ISSUE(ss, buf)                                                        \
    {                                                                         \
        const int cb_ = (kc * 4 + (ss)) * 128;                                \
        char* base = &lds[buf][0];                                            \
        gl_lds16(Asrc0 + cb_, base + w * 1024);                               \
        gl_lds16(Asrc1 + cb_, base + 8192 + w * 1024);                        \
        gl_lds16(Wsrc  + cb_, base + 16384 + w * 1024);                       \
    }

    f32x4 acc[2][2];
#pragma unroll
    for (int a = 0; a < 2; ++a)
#pragma unroll
        for (int bq = 0; bq < 2; ++bq) acc[a][bq] = (f32x4){0.f, 0.f, 0.f, 0.f};

    const int mq = w >> 1, nq = w & 1;
    const int r16 = l & 15, k16 = l >> 4;

    ISSUE(0, 0)
    ISSUE(1, 1)

#pragma unroll
    for (int s = 0; s < 4; ++s) {
        if (s < 3) { asm volatile("s_waitcnt vmcnt(3)" ::: "memory"); }
        else       { asm volatile("s_waitcnt vmcnt(0)" ::: "memory"); }
        __builtin_amdgcn_s_barrier();
        asm volatile("" ::: "memory");

        const char* Ab = &lds[s & 1][0];
        const char* Wb = &lds[s & 1][16384];
#pragma unroll
        for (int ks = 0; ks < 2; ++ks) {
            const int qf = ks * 4 + k16;
            bf16x8 bf[2], af[2];
#pragma unroll
            for (int bq = 0; bq < 2; ++bq) {
                const int rn = nq * 32 + bq * 16 + r16;
                bf[bq] = *reinterpret_cast<const bf16x8*>(Wb + rn * 128 + ((qf ^ (rn & 7)) << 4));
            }
#pragma unroll
            for (int a = 0; a < 2; ++a) {
                const int rm = mq * 32 + a * 16 + r16;
                af[a] = *reinterpret_cast<const bf16x8*>(Ab + rm * 128 + ((qf ^ (rm & 7)) << 4));
            }
#pragma unroll
            for (int a = 0; a < 2; ++a)
#pragma unroll
                for (int bq = 0; bq < 2; ++bq)
                    acc[a][bq] = __builtin_amdgcn_mfma_f32_16x16x32_bf16(af[a], bf[bq], acc[a][bq], 0, 0, 0);
        }

        __builtin_amdgcn_s_barrier();
        asm volatile("" ::: "memory");
        if (s == 0) ISSUE(2, 0)
        if (s == 1) ISSUE(3, 1)
    }
#undef ISSUE

    // epilogue: bf16 partial [kc][b][o]
    ushort_t* pp = partial + (size_t)kc * (B_DIM * OUT1);
#pragma unroll
    for (int a = 0; a < 2; ++a) {
#pragma unroll
        for (int bq = 0; bq < 2; ++bq) {
            const int col = o0 + nq * 32 + bq * 16 + r16;
#pragma unroll
            for (int r = 0; r < 4; ++r) {
                const int row = mq * 32 + a * 16 + k16 * 4 + r;
                pp[(size_t)row * OUT1 + col] = f2bf(acc[a][bq][r]);
            }
        }
    }
}

// ---------------------------------------------------------------------------
// klayer2r: unchanged from R12.  One block per b, 512 thr (8 waves).
// ---------------------------------------------------------------------------
__global__ __launch_bounds__(512) void klayer2r(const ushort_t* __restrict__ partial,
                                                const float* __restrict__ coef2,
                                                const float* __restrict__ sb2,
                                                const float* __restrict__ ssp2,
                                                float* __restrict__ out) {
    const int b = blockIdx.x;
    const int t = threadIdx.x;
    const int w = t >> 6, l = t & 63;
    __shared__ float sums[8][OUT1];
    __shared__ float red[4][OUT2];

    f32x4 s = {0.f, 0.f, 0.f, 0.f};
    const ushort_t* pb = partial + (size_t)b * OUT1 + l * 4;
#pragma unroll
    for (int c = 0; c < 13; ++c) {
        ushort4 v = *reinterpret_cast<const ushort4*>(
            pb + (size_t)(w + 8 * c) * (B_DIM * OUT1));
        s[0] += bf2f(v.x); s[1] += bf2f(v.y); s[2] += bf2f(v.z); s[3] += bf2f(v.w);
    }
    if (w < 4) {
        ushort4 v = *reinterpret_cast<const ushort4*>(
            pb + (size_t)(w + 104) * (B_DIM * OUT1));
        s[0] += bf2f(v.x); s[1] += bf2f(v.y); s[2] += bf2f(v.z); s[3] += bf2f(v.w);
    }
    *reinterpret_cast<float4*>(&sums[w][l * 4]) = (float4){s[0], s[1], s[2], s[3]};
    __syncthreads();

    if (t < OUT1) {
        const float hv = sums[0][t] + sums[1][t] + sums[2][t] + sums[3][t] +
                         sums[4][t] + sums[5][t] + sums[6][t] + sums[7][t];
        const float sh = selu_f(hv);
        float w8[8], sil;
        basis_silu(sh, w8, sil);

        float accs[OUT2];
#pragma unroll
        for (int oo = 0; oo < OUT2; ++oo) {
            const float* cp = coef2 + ((size_t)oo * OUT1 + t) * NB;
            float4 c0 = *reinterpret_cast<const float4*>(cp);
            float4 c1 = *reinterpret_cast<const float4*>(cp + 4);
            float dot = w8[0] * c0.x + w8[1] * c0.y + w8[2] * c0.z + w8[3] * c0.w +
                        w8[4] * c1.x + w8[5] * c1.y + w8[6] * c1.z + w8[7] * c1.w;
            accs[oo] = sb2[oo * OUT1 + t] * sil + ssp2[oo * OUT1 + t] * dot;
        }

#pragma unroll
        for (int oo = 0; oo < OUT2; ++oo) {
            float v = accs[oo];
#pragma unroll
            for (int off = 32; off >= 1; off >>= 1) v += __shfl_xor(v, off, 64);
            if (l == 0) red[w][oo] = v;
        }
    }
    __syncthreads();
    if (t < OUT2)
        out[b * OUT2 + t] = red[0][t] + red[1][t] + red[2][t] + red[3][t];
}

// ---------------------------------------------------------------------------
extern "C" void kernel_launch(void* const* d_in, const int* in_sizes, int n_in,
                              void* d_out, int out_size, void* d_ws, size_t ws_size,
                              hipStream_t stream) {
    const float* x     = (const float*)d_in[0];
    const float* coef1 = (const float*)d_in[1];
    const float* sb1   = (const float*)d_in[2];
    const float* ssp1  = (const float*)d_in[3];
    const float* coef2 = (const float*)d_in[4];
    const float* sb2   = (const float*)d_in[5];
    const float* ssp2  = (const float*)d_in[6];
    float* out = (float*)d_out;

    char*     Ag      = (char*)d_ws;                             // 7,077,888 B
    char*     Wg      = Ag + (size_t)B_DIM * ROWB;               // 14,155,776 B
    ushort_t* partial = (ushort_t*)(Wg + (size_t)OUT1 * ROWB);   // 7,077,888 B

    kconv_a<<<384, 256, 0, stream>>>(x, Ag);
    kconv_w<<<768, 256, 0, stream>>>(coef1, sb1, ssp1, Wg);
    kgemm<<<dim3(OUT1 / BN, SPLITK), 512, 0, stream>>>(Ag, Wg, partial);
    klayer2r<<<B_DIM, 512, 0, stream>>>(partial, coef2, sb2, ssp2, out);
}